// Round 7
// baseline (242.090 us; speedup 1.0000x reference)
//
#include <hip/hip_runtime.h>
#include <math.h>

typedef unsigned short u16;
typedef __bf16 bf16x8 __attribute__((ext_vector_type(8)));
typedef float f32x4 __attribute__((ext_vector_type(4)));
typedef unsigned short u16x4 __attribute__((ext_vector_type(4)));
typedef unsigned short u16x8 __attribute__((ext_vector_type(8)));

__device__ __forceinline__ u16 f2bf(float f) {
    unsigned int u = __float_as_uint(f);
    return (u16)((u + 0x7FFF + ((u >> 16) & 1)) >> 16);
}

#define BAR() do { __builtin_amdgcn_sched_barrier(0); __builtin_amdgcn_s_barrier(); __builtin_amdgcn_sched_barrier(0); } while (0)

// ===========================================================================
// 256x256 8-wave GEMM core, BK=32, 4-deep LDS pipeline (prefetch 3 K-tiles).
// A: logical row m -> global row baseA + m*rsA, k-contig (ldA).
// B: logical row n -> global row n0 + n, k-contig (ldB).
// LDS = 4 bufs x (A 16KB + B 16KB) = 128KB. 2 phases per K-tile, 16 MFMA each.
//
// LDS layout: [kc][row] -- 16B chunk (row, kc) stored at chunk index
// kc*256 + row. Read addr for lane (p,g) = (g*256 + row)*16 B ->
// bank = 4*row mod 32: rows p and p+8 alias = 2 lanes/bank = FREE (m136).
// (Round-6's [row][kc] at 64B row stride was an 8-way conflict, 4.7M counted.)
// Logical k map unchanged: chunk kc holds k=8kc..8kc+7, read at g=kc.
//
// Counted waits: entering tile t, instrs issued after B(t) are
// A/B(t+1), A/B(t+2), A(t+3) = 10 (steady); tail r=NT-1-t: 2->8, 1->4, 0->0.
// Buffer reuse safety: stg of tile t+3 writes buf (t-1)&3, issued after the
// end-of-tile-(t-1) barrier -> all reads of that buf are complete.
// ===========================================================================
__device__ __forceinline__ void stg(
    const u16* __restrict__ g, int ld, int row0, int rstride, int kt,
    u16* lds, int w, int l)
{
    #pragma unroll
    for (int qq = 0; qq < 2; ++qq) {
        const int c0 = qq * 512 + w * 64;        // wave-uniform chunk base
        const int c  = c0 + l;                   // chunk: kc = c>>8, row = c&255
        const int row = c & 255, kc = c >> 8;
        const u16* src = g + (size_t)(row0 + row * rstride) * ld + kt + kc * 8;
        __builtin_amdgcn_global_load_lds(
            (const __attribute__((address_space(1))) unsigned int*)src,
            (__attribute__((address_space(3))) unsigned int*)(lds + (size_t)c0 * 8),
            16, 0, 0);
    }
}

template<int NT>
__device__ __forceinline__ void gemm256(
    const u16* __restrict__ Ag, int ldA, int baseA, int rsA,
    const u16* __restrict__ Bg, int ldB, int n0,
    u16* sm, f32x4 (&acc)[8][4])
{
    const int tid = threadIdx.x;
    const int l = tid & 63, w = tid >> 6;
    const int p = l & 15, g = l >> 4;
    const int wm = (w >> 2) * 128;   // 2 M-waves
    const int wn = (w & 3) * 64;     // 4 N-waves

    // prologue: stage tiles 0..2 (12 load-instrs/wave outstanding)
    #pragma unroll
    for (int t = 0; t < 3; ++t) {
        u16* buf = sm + (t & 3) * 16384;
        stg(Ag, ldA, baseA, rsA, t * 32, buf, w, l);
        stg(Bg, ldB, n0, 1, t * 32, buf + 8192, w, l);
    }

    #pragma unroll
    for (int t = 0; t < NT; ++t) {
        u16* bufA = sm + (t & 3) * 16384;
        u16* bufB = bufA + 8192;
        u16* nbuf = sm + ((t + 3) & 3) * 16384;

        // ---- phase 1: stage A(t+3); counted gate for tile t; half 1 ----
        if (t + 3 < NT) stg(Ag, ldA, baseA, rsA, (t + 3) * 32, nbuf, w, l);
        {
            const int r = NT - 1 - t;
            if (r >= 3)      asm volatile("s_waitcnt vmcnt(10)" ::: "memory");
            else if (r == 2) asm volatile("s_waitcnt vmcnt(8)"  ::: "memory");
            else if (r == 1) asm volatile("s_waitcnt vmcnt(4)"  ::: "memory");
            else             asm volatile("s_waitcnt vmcnt(0)"  ::: "memory");
        }
        BAR();
        bf16x8 bfr[4];
        #pragma unroll
        for (int nf = 0; nf < 4; ++nf) {
            int row = wn + nf * 16 + p;
            bfr[nf] = *(const bf16x8*)(bufB + (size_t)(g * 256 + row) * 8);
        }
        {
            bf16x8 af[4];
            #pragma unroll
            for (int i = 0; i < 4; ++i) {
                int row = wm + i * 16 + p;
                af[i] = *(const bf16x8*)(bufA + (size_t)(g * 256 + row) * 8);
            }
            __builtin_amdgcn_s_setprio(1);
            #pragma unroll
            for (int i = 0; i < 4; ++i)
                #pragma unroll
                for (int nf = 0; nf < 4; ++nf)
                    acc[i][nf] = __builtin_amdgcn_mfma_f32_16x16x32_bf16(af[i], bfr[nf], acc[i][nf], 0, 0, 0);
            __builtin_amdgcn_s_setprio(0);
        }
        // ---- phase 2: stage B(t+3); half 2 ----
        if (t + 3 < NT) stg(Bg, ldB, n0, 1, (t + 3) * 32, nbuf + 8192, w, l);
        {
            bf16x8 af[4];
            #pragma unroll
            for (int i = 0; i < 4; ++i) {
                int row = wm + (4 + i) * 16 + p;
                af[i] = *(const bf16x8*)(bufA + (size_t)(g * 256 + row) * 8);
            }
            __builtin_amdgcn_s_setprio(1);
            #pragma unroll
            for (int i = 0; i < 4; ++i)
                #pragma unroll
                for (int nf = 0; nf < 4; ++nf)
                    acc[4 + i][nf] = __builtin_amdgcn_mfma_f32_16x16x32_bf16(af[i], bfr[nf], acc[4 + i][nf], 0, 0, 0);
            __builtin_amdgcn_s_setprio(0);
        }
        BAR();
    }
}

// ---------------------------------------------------------------------------
// K0: merged prep. z<16: xT[b][n][c] (bf16) = x[b][c][n] (f32).
// z==16: weight f32->bf16 conversion (512 blocks exactly).
// ---------------------------------------------------------------------------
__global__ __launch_bounds__(256) void k0_prep(
    const float* __restrict__ x, u16* __restrict__ xT,
    const float* __restrict__ Wq, const float* __restrict__ Wk,
    const float* __restrict__ Wv, const float* __restrict__ Wo,
    u16* __restrict__ wqk, u16* __restrict__ wv, u16* __restrict__ wo)
{
    const int tid = threadIdx.x;
    if (blockIdx.z == 16) {
        const int bid = blockIdx.y * 64 + blockIdx.x;   // 0..511
        const int sel = bid >> 7;
        const int sub = bid & 127;
        const float* s = sel == 0 ? Wq : sel == 1 ? Wk : sel == 2 ? Wv : Wo;
        u16* d = sel == 0 ? wqk : sel == 1 ? (wqk + 131072) : sel == 2 ? wv : wo;
        int i = (sub * 256 + tid) * 4;
        float4 v = *(const float4*)(s + i);
        u16x4 u = {f2bf(v.x), f2bf(v.y), f2bf(v.z), f2bf(v.w)};
        *(u16x4*)(d + i) = u;
        return;
    }
    __shared__ float Tx[64 * 65];
    const int b = blockIdx.z, c0 = blockIdx.y * 64, n0 = blockIdx.x * 64;
    const float* xb = x + (size_t)b * 512 * 4096;
    #pragma unroll
    for (int r = 0; r < 4; ++r) {
        int crow = (tid >> 4) + r * 16;
        int ncol = (tid & 15) * 4;
        float4 v = *(const float4*)(xb + (size_t)(c0 + crow) * 4096 + n0 + ncol);
        Tx[(ncol + 0) * 65 + crow] = v.x;
        Tx[(ncol + 1) * 65 + crow] = v.y;
        Tx[(ncol + 2) * 65 + crow] = v.z;
        Tx[(ncol + 3) * 65 + crow] = v.w;
    }
    __syncthreads();
    u16* ob = xT + (size_t)b * 4096 * 512;
    #pragma unroll
    for (int cc = 0; cc < 2; ++cc) {
        int id = cc * 256 + tid;
        int nrow = id >> 3;
        int cch = (id & 7) * 8;
        u16x8 u;
        #pragma unroll
        for (int j = 0; j < 8; ++j) u[j] = f2bf(Tx[nrow * 65 + cch + j]);
        *(u16x8*)(ob + (size_t)(n0 + nrow) * 512 + c0 + cch) = u;
    }
}

// ---------------------------------------------------------------------------
// K1: merged q/k/v. grid (16, 3, 16), 512 threads.
// y<2:  q,k = wqk . xT^T + bias  (m0 = y*256, n0 = x*256)
// y==2: vT[n][d] = xT[n][:] . Wv[d][:] + bv[d]  (m0 = x*256 over spatial)
// ---------------------------------------------------------------------------
__global__ __launch_bounds__(512, 2) void k1_qkv(
    const u16* __restrict__ wqk, const u16* __restrict__ wv,
    const float* __restrict__ bq, const float* __restrict__ bk, const float* __restrict__ bv,
    const u16* __restrict__ xT, u16* __restrict__ q, u16* __restrict__ kmat,
    u16* __restrict__ vT)
{
    __shared__ u16 sm[65536];
    const int b = blockIdx.z;
    const int y = blockIdx.y;
    const u16* xb = xT + (size_t)b * 4096 * 512;

    const int tid = threadIdx.x;
    const int l = tid & 63, w = tid >> 6;
    const int p = l & 15, g = l >> 4;
    const int wm = (w >> 2) * 128, wn = (w & 3) * 64;

    f32x4 acc[8][4] = {};

    if (y < 2) {
        const int m0 = y * 256;
        const int n0 = blockIdx.x * 256;
        gemm256<16>(wqk, 512, m0, 1, xb, 512, n0, sm, acc);

        const float* bias = (y == 0) ? bq : bk;
        u16* outp = ((y == 0) ? q : kmat) + ((size_t)b << 20);
        #pragma unroll
        for (int mf = 0; mf < 8; ++mf)
            #pragma unroll
            for (int nf = 0; nf < 4; ++nf) {
                int n = n0 + wn + nf * 16 + p;
                #pragma unroll
                for (int r = 0; r < 4; ++r) {
                    int mloc = wm + mf * 16 + g * 4 + r;
                    outp[(size_t)mloc * 4096 + n] = f2bf(acc[mf][nf][r] + bias[mloc]);
                }
            }
    } else {
        const int m0 = blockIdx.x * 256;
        gemm256<16>(xb, 512, m0, 1, wv, 512, 0, sm, acc);

        u16* outp = vT + ((size_t)b << 20);
        #pragma unroll
        for (int nf = 0; nf < 4; ++nf) {
            int d = wn + nf * 16 + p;
            float bvv = bv[d];
            #pragma unroll
            for (int mf = 0; mf < 8; ++mf) {
                #pragma unroll
                for (int r = 0; r < 4; ++r) {
                    int row = m0 + wm + mf * 16 + g * 4 + r;
                    outp[(size_t)row * 256 + d] = f2bf(acc[mf][nf][r] + bvv);
                }
            }
        }
    }
}

// ---------------------------------------------------------------------------
// K2: score partials, split-K=8. grid (8=split, 1, 16=b), 512 threads.
// K-slice = split*512 (pointer offset), NT=16.
// ---------------------------------------------------------------------------
__global__ __launch_bounds__(512, 2) void k2_scores(
    const u16* __restrict__ q, const u16* __restrict__ kmat, float* __restrict__ spart)
{
    __shared__ u16 sm[65536];
    const int b = blockIdx.z;
    const int split = blockIdx.x;
    const u16* A = q    + ((size_t)b << 20) + split * 512;
    const u16* B = kmat + ((size_t)b << 20) + split * 512;

    f32x4 acc[8][4] = {};
    gemm256<16>(A, 4096, 0, 1, B, 4096, 0, sm, acc);

    const int tid = threadIdx.x;
    const int l = tid & 63, w = tid >> 6;
    const int p = l & 15, g = l >> 4;
    const int wm = (w >> 2) * 128, wn = (w & 3) * 64;

    float* sp = spart + ((size_t)split * 16 + b) * 65536;
    #pragma unroll
    for (int mf = 0; mf < 8; ++mf)
        #pragma unroll
        for (int nf = 0; nf < 4; ++nf) {
            int n = wn + nf * 16 + p;
            #pragma unroll
            for (int r = 0; r < 4; ++r) {
                int m = wm + mf * 16 + g * 4 + r;
                sp[(size_t)m * 256 + n] = acc[mf][nf][r] * 0.015625f;
            }
        }
}

// ---------------------------------------------------------------------------
// K3: reduce 8 split partials + softmax over d -> bf16 attn
// ---------------------------------------------------------------------------
__global__ __launch_bounds__(256) void k3_softmax(
    const float* __restrict__ sp, u16* __restrict__ attn)
{
    const int row = blockIdx.x;
    const int tid = threadIdx.x;
    const size_t STRIDE = (size_t)16 * 65536;
    const size_t base = (size_t)row * 256 + tid;

    float s = 0.f;
    #pragma unroll
    for (int i = 0; i < 8; ++i) s += sp[base + i * STRIDE];

    __shared__ float red[4];
    float m = s;
    #pragma unroll
    for (int off = 32; off >= 1; off >>= 1) m = fmaxf(m, __shfl_xor(m, off));
    if ((tid & 63) == 0) red[tid >> 6] = m;
    __syncthreads();
    m = fmaxf(fmaxf(red[0], red[1]), fmaxf(red[2], red[3]));

    float e = expf(s - m);
    float t = e;
    #pragma unroll
    for (int off = 32; off >= 1; off >>= 1) t += __shfl_xor(t, off);
    __syncthreads();
    if ((tid & 63) == 0) red[tid >> 6] = t;
    __syncthreads();
    t = red[0] + red[1] + red[2] + red[3];

    attn[base] = f2bf(e / t);
}

// ---------------------------------------------------------------------------
// K4: outT3[b][sh][co][nh] = sum_d attn[b][co][d] * vT[b][16nh+sh][d]
// Per (b,sh): M=256 (nh via rstride-16 A rows), N=256 (co), K=256 (d), NT=8.
// grid (16=sh, 1, 16=b), 512 threads.
// ---------------------------------------------------------------------------
__global__ __launch_bounds__(512, 2) void k4_pv(
    const u16* __restrict__ attn, const u16* __restrict__ vT, u16* __restrict__ outT3)
{
    __shared__ u16 sm[65536];
    const int b  = blockIdx.z;
    const int sh = blockIdx.x;
    const u16* A = vT   + ((size_t)b << 20);   // rows 16m+sh
    const u16* B = attn + ((size_t)b << 16);

    f32x4 acc[8][4] = {};
    gemm256<8>(A, 256, sh, 16, B, 256, 0, sm, acc);

    const int tid = threadIdx.x;
    const int l = tid & 63, w = tid >> 6;
    const int p = l & 15, g = l >> 4;
    const int wm = (w >> 2) * 128, wn = (w & 3) * 64;

    u16* outp = outT3 + (((size_t)b * 16 + sh) << 16);
    #pragma unroll
    for (int mf = 0; mf < 8; ++mf)
        #pragma unroll
        for (int nf = 0; nf < 4; ++nf) {
            int co  = wn + nf * 16 + p;
            int nh0 = wm + mf * 16 + g * 4;
            u16x4 u = {f2bf(acc[mf][nf][0]), f2bf(acc[mf][nf][1]),
                       f2bf(acc[mf][nf][2]), f2bf(acc[mf][nf][3])};
            *(u16x4*)(outp + (size_t)co * 256 + nh0) = u;
        }
}

// ---------------------------------------------------------------------------
// K5: final[b][c][sh*256+slo] = sum_nh Wo[c][nh] * outT3[b][sh][slo][nh] + bo[c]
// Per (b,sh): M=512 (c), N=256 (slo), K=256 (nh), NT=8. grid (1, 2, 256).
// ---------------------------------------------------------------------------
__global__ __launch_bounds__(512, 2) void k5_final(
    const u16* __restrict__ wo, const float* __restrict__ bo,
    const u16* __restrict__ outT3, float* __restrict__ out)
{
    __shared__ u16 sm[65536];
    const int bz = blockIdx.z;               // b*16 + sh
    const int b  = bz >> 4, sh = bz & 15;
    const int m0 = blockIdx.y * 256;
    const u16* B = outT3 + ((size_t)bz << 16);

    f32x4 acc[8][4] = {};
    gemm256<8>(wo, 256, m0, 1, B, 256, 0, sm, acc);

    const int tid = threadIdx.x;
    const int l = tid & 63, w = tid >> 6;
    const int p = l & 15, g = l >> 4;
    const int wm = (w >> 2) * 128, wn = (w & 3) * 64;

    float* ob = out + (size_t)b * 2097152 + (size_t)sh * 256;
    #pragma unroll
    for (int mf = 0; mf < 8; ++mf)
        #pragma unroll
        for (int nf = 0; nf < 4; ++nf) {
            int slo = wn + nf * 16 + p;
            #pragma unroll
            for (int r = 0; r < 4; ++r) {
                int m = m0 + wm + mf * 16 + g * 4 + r;
                ob[(size_t)m * 4096 + slo] = acc[mf][nf][r] + bo[m];
            }
        }
}

// ---------------------------------------------------------------------------
extern "C" void kernel_launch(void* const* d_in, const int* in_sizes, int n_in,
                              void* d_out, int out_size, void* d_ws, size_t ws_size,
                              hipStream_t stream) {
    (void)in_sizes; (void)n_in; (void)out_size; (void)ws_size;
    const float* x  = (const float*)d_in[0];
    const float* Wq = (const float*)d_in[1];
    const float* bq = (const float*)d_in[2];
    const float* Wk = (const float*)d_in[3];
    const float* bk = (const float*)d_in[4];
    const float* Wv = (const float*)d_in[5];
    const float* bv = (const float*)d_in[6];
    const float* Wo = (const float*)d_in[7];
    const float* bo = (const float*)d_in[8];
    float* out = (float*)d_out;

    char* ws = (char*)d_ws;
    u16* xT   = (u16*)(ws + 0);             // 67.1MB, dead after k1
    u16* q    = (u16*)(ws + 67108864);      // 33.5MB, dead after k2
    u16* kmat = (u16*)(ws + 100663296);     // 33.5MB, dead after k2
    u16* vT   = (u16*)(ws + 134217728);     // 33.5MB, dead after k4
    float* spart = (float*)(ws + 0);        // 33.5MB f32 (8 splits), aliases xT
    u16* attn    = (u16*)(ws + 67108864);   // 2MB, aliases q
    u16* outT3   = (u16*)(ws + 100663296);  // 33.5MB, aliases kmat
    u16* wqk  = (u16*)(ws + 167772160);     // 512KB [512][512] (q rows then k rows)
    u16* wv   = (u16*)(ws + 168296448);     // 256KB [256][512]
    u16* wo   = (u16*)(ws + 168558592);     // 256KB [512][256]

    k0_prep   <<<dim3(64, 8, 17), dim3(256), 0, stream>>>(x, xT, Wq, Wk, Wv, Wo, wqk, wv, wo);
    k1_qkv    <<<dim3(16, 3, 16), dim3(512), 0, stream>>>(wqk, wv, bq, bk, bv, xT, q, kmat, vT);
    k2_scores <<<dim3(8, 1, 16),  dim3(512), 0, stream>>>(q, kmat, spart);
    k3_softmax<<<dim3(4096),      dim3(256), 0, stream>>>(spart, attn);
    k4_pv     <<<dim3(16, 1, 16), dim3(512), 0, stream>>>(attn, vT, outT3);
    k5_final  <<<dim3(1, 2, 256), dim3(512), 0, stream>>>(wo, bo, outT3, out);
}

// Round 8
// 196.250 us; speedup vs baseline: 1.2336x; 1.2336x over previous
//
#include <hip/hip_runtime.h>
#include <math.h>

typedef unsigned short u16;
typedef __bf16 bf16x8 __attribute__((ext_vector_type(8)));
typedef float f32x4 __attribute__((ext_vector_type(4)));
typedef unsigned short u16x4 __attribute__((ext_vector_type(4)));
typedef unsigned short u16x8 __attribute__((ext_vector_type(8)));

__device__ __forceinline__ u16 f2bf(float f) {
    unsigned int u = __float_as_uint(f);
    return (u16)((u + 0x7FFF + ((u >> 16) & 1)) >> 16);
}

#define BAR() do { __builtin_amdgcn_sched_barrier(0); __builtin_amdgcn_s_barrier(); __builtin_amdgcn_sched_barrier(0); } while (0)

// ===========================================================================
// 256x256 8-wave GEMM core, BK=32, 4-deep LDS pipeline (prefetch 3 K-tiles).
// A: logical row m -> global row baseA + m*rsA, k-contig (ldA).
// B: logical row n -> global row n0 + n, k-contig (ldB).
// LDS = 4 bufs x (A 16KB + B 16KB) = 128KB. 2 phases per K-tile, 16 MFMA each.
//
// LDS chunk map (16B chunks): chunk(row, kc) stored at  row*4 + (kc ^ f(row)),
// f(row) = (row>>1)&3.
//  * Staging: consecutive chunk indices c = 4 chunks of one row, permuted
//    within the row's 64B span -> 16 x 64B coalesced requests per
//    global_load_lds (r7's [kc][row] was 64 x 16B scattered -> L2 choke).
//  * Reads (quarter-wave = fixed g): lane p -> bank group
//    4(p&1) + (g ^ ((p>>1)&3)); p=(b,h) covers all 8 groups exactly twice
//    -> 2 lanes/bank = free (m136). (r6's un-XORed [row][kc] collapsed to 2
//    groups -> 8-way, 4.7M conflicts.)
//  * Content check: stored chunk at read index row*4+(g^f) holds
//    kc = (g^f)^f = g -> logical k map unchanged, bit-identical numerics.
//
// Counted waits (unchanged from r6/r7, verified ledger): entering tile t,
// instrs issued after B(t) are A/B(t+1), A/B(t+2), A(t+3) = 10 (steady);
// tail r=NT-1-t: 2->8, 1->4, 0->0.
// Buffer reuse safety: stg of tile t+3 writes buf (t-1)&3, issued after the
// end-of-tile-(t-1) barrier -> all reads of that buf are complete.
// ===========================================================================
__device__ __forceinline__ void stg(
    const u16* __restrict__ g, int ld, int row0, int rstride, int kt,
    u16* lds, int w, int l)
{
    #pragma unroll
    for (int qq = 0; qq < 2; ++qq) {
        const int c0 = qq * 512 + w * 64;        // wave-uniform chunk base
        const int c  = c0 + l;                   // chunk: row = c>>2, kcs = c&3
        const int row = c >> 2, kcs = c & 3;
        const int kc  = kcs ^ ((row >> 1) & 3);  // pre-swizzled global source
        const u16* src = g + (size_t)(row0 + row * rstride) * ld + kt + kc * 8;
        __builtin_amdgcn_global_load_lds(
            (const __attribute__((address_space(1))) unsigned int*)src,
            (__attribute__((address_space(3))) unsigned int*)(lds + (size_t)c0 * 8),
            16, 0, 0);
    }
}

template<int NT>
__device__ __forceinline__ void gemm256(
    const u16* __restrict__ Ag, int ldA, int baseA, int rsA,
    const u16* __restrict__ Bg, int ldB, int n0,
    u16* sm, f32x4 (&acc)[8][4])
{
    const int tid = threadIdx.x;
    const int l = tid & 63, w = tid >> 6;
    const int p = l & 15, g = l >> 4;
    const int wm = (w >> 2) * 128;   // 2 M-waves
    const int wn = (w & 3) * 64;     // 4 N-waves

    // prologue: stage tiles 0..2 (12 load-instrs/wave outstanding)
    #pragma unroll
    for (int t = 0; t < 3; ++t) {
        u16* buf = sm + (t & 3) * 16384;
        stg(Ag, ldA, baseA, rsA, t * 32, buf, w, l);
        stg(Bg, ldB, n0, 1, t * 32, buf + 8192, w, l);
    }

    #pragma unroll
    for (int t = 0; t < NT; ++t) {
        u16* bufA = sm + (t & 3) * 16384;
        u16* bufB = bufA + 8192;
        u16* nbuf = sm + ((t + 3) & 3) * 16384;

        // ---- phase 1: stage A(t+3); counted gate for tile t; half 1 ----
        if (t + 3 < NT) stg(Ag, ldA, baseA, rsA, (t + 3) * 32, nbuf, w, l);
        {
            const int r = NT - 1 - t;
            if (r >= 3)      asm volatile("s_waitcnt vmcnt(10)" ::: "memory");
            else if (r == 2) asm volatile("s_waitcnt vmcnt(8)"  ::: "memory");
            else if (r == 1) asm volatile("s_waitcnt vmcnt(4)"  ::: "memory");
            else             asm volatile("s_waitcnt vmcnt(0)"  ::: "memory");
        }
        BAR();
        bf16x8 bfr[4];
        #pragma unroll
        for (int nf = 0; nf < 4; ++nf) {
            int row = wn + nf * 16 + p;
            bfr[nf] = *(const bf16x8*)(bufB + (size_t)(row * 4 + (g ^ ((row >> 1) & 3))) * 8);
        }
        {
            bf16x8 af[4];
            #pragma unroll
            for (int i = 0; i < 4; ++i) {
                int row = wm + i * 16 + p;
                af[i] = *(const bf16x8*)(bufA + (size_t)(row * 4 + (g ^ ((row >> 1) & 3))) * 8);
            }
            __builtin_amdgcn_s_setprio(1);
            #pragma unroll
            for (int i = 0; i < 4; ++i)
                #pragma unroll
                for (int nf = 0; nf < 4; ++nf)
                    acc[i][nf] = __builtin_amdgcn_mfma_f32_16x16x32_bf16(af[i], bfr[nf], acc[i][nf], 0, 0, 0);
            __builtin_amdgcn_s_setprio(0);
        }
        // ---- phase 2: stage B(t+3); half 2 ----
        if (t + 3 < NT) stg(Bg, ldB, n0, 1, (t + 3) * 32, nbuf + 8192, w, l);
        {
            bf16x8 af[4];
            #pragma unroll
            for (int i = 0; i < 4; ++i) {
                int row = wm + (4 + i) * 16 + p;
                af[i] = *(const bf16x8*)(bufA + (size_t)(row * 4 + (g ^ ((row >> 1) & 3))) * 8);
            }
            __builtin_amdgcn_s_setprio(1);
            #pragma unroll
            for (int i = 0; i < 4; ++i)
                #pragma unroll
                for (int nf = 0; nf < 4; ++nf)
                    acc[4 + i][nf] = __builtin_amdgcn_mfma_f32_16x16x32_bf16(af[i], bfr[nf], acc[4 + i][nf], 0, 0, 0);
            __builtin_amdgcn_s_setprio(0);
        }
        BAR();
    }
}

// ---------------------------------------------------------------------------
// K0: merged prep. z<16: xT[b][n][c] (bf16) = x[b][c][n] (f32).
// z==16: weight f32->bf16 conversion (512 blocks exactly).
// ---------------------------------------------------------------------------
__global__ __launch_bounds__(256) void k0_prep(
    const float* __restrict__ x, u16* __restrict__ xT,
    const float* __restrict__ Wq, const float* __restrict__ Wk,
    const float* __restrict__ Wv, const float* __restrict__ Wo,
    u16* __restrict__ wqk, u16* __restrict__ wv, u16* __restrict__ wo)
{
    const int tid = threadIdx.x;
    if (blockIdx.z == 16) {
        const int bid = blockIdx.y * 64 + blockIdx.x;   // 0..511
        const int sel = bid >> 7;
        const int sub = bid & 127;
        const float* s = sel == 0 ? Wq : sel == 1 ? Wk : sel == 2 ? Wv : Wo;
        u16* d = sel == 0 ? wqk : sel == 1 ? (wqk + 131072) : sel == 2 ? wv : wo;
        int i = (sub * 256 + tid) * 4;
        float4 v = *(const float4*)(s + i);
        u16x4 u = {f2bf(v.x), f2bf(v.y), f2bf(v.z), f2bf(v.w)};
        *(u16x4*)(d + i) = u;
        return;
    }
    __shared__ float Tx[64 * 65];
    const int b = blockIdx.z, c0 = blockIdx.y * 64, n0 = blockIdx.x * 64;
    const float* xb = x + (size_t)b * 512 * 4096;
    #pragma unroll
    for (int r = 0; r < 4; ++r) {
        int crow = (tid >> 4) + r * 16;
        int ncol = (tid & 15) * 4;
        float4 v = *(const float4*)(xb + (size_t)(c0 + crow) * 4096 + n0 + ncol);
        Tx[(ncol + 0) * 65 + crow] = v.x;
        Tx[(ncol + 1) * 65 + crow] = v.y;
        Tx[(ncol + 2) * 65 + crow] = v.z;
        Tx[(ncol + 3) * 65 + crow] = v.w;
    }
    __syncthreads();
    u16* ob = xT + (size_t)b * 4096 * 512;
    #pragma unroll
    for (int cc = 0; cc < 2; ++cc) {
        int id = cc * 256 + tid;
        int nrow = id >> 3;
        int cch = (id & 7) * 8;
        u16x8 u;
        #pragma unroll
        for (int j = 0; j < 8; ++j) u[j] = f2bf(Tx[nrow * 65 + cch + j]);
        *(u16x8*)(ob + (size_t)(n0 + nrow) * 512 + c0 + cch) = u;
    }
}

// ---------------------------------------------------------------------------
// K1: merged q/k/v. grid (16, 3, 16), 512 threads.
// y<2:  q,k = wqk . xT^T + bias  (m0 = y*256, n0 = x*256)
// y==2: vT[n][d] = xT[n][:] . Wv[d][:] + bv[d]  (m0 = x*256 over spatial)
// ---------------------------------------------------------------------------
__global__ __launch_bounds__(512, 2) void k1_qkv(
    const u16* __restrict__ wqk, const u16* __restrict__ wv,
    const float* __restrict__ bq, const float* __restrict__ bk, const float* __restrict__ bv,
    const u16* __restrict__ xT, u16* __restrict__ q, u16* __restrict__ kmat,
    u16* __restrict__ vT)
{
    __shared__ u16 sm[65536];
    const int b = blockIdx.z;
    const int y = blockIdx.y;
    const u16* xb = xT + (size_t)b * 4096 * 512;

    const int tid = threadIdx.x;
    const int l = tid & 63, w = tid >> 6;
    const int p = l & 15, g = l >> 4;
    const int wm = (w >> 2) * 128, wn = (w & 3) * 64;

    f32x4 acc[8][4] = {};

    if (y < 2) {
        const int m0 = y * 256;
        const int n0 = blockIdx.x * 256;
        gemm256<16>(wqk, 512, m0, 1, xb, 512, n0, sm, acc);

        const float* bias = (y == 0) ? bq : bk;
        u16* outp = ((y == 0) ? q : kmat) + ((size_t)b << 20);
        #pragma unroll
        for (int mf = 0; mf < 8; ++mf)
            #pragma unroll
            for (int nf = 0; nf < 4; ++nf) {
                int n = n0 + wn + nf * 16 + p;
                #pragma unroll
                for (int r = 0; r < 4; ++r) {
                    int mloc = wm + mf * 16 + g * 4 + r;
                    outp[(size_t)mloc * 4096 + n] = f2bf(acc[mf][nf][r] + bias[mloc]);
                }
            }
    } else {
        const int m0 = blockIdx.x * 256;
        gemm256<16>(xb, 512, m0, 1, wv, 512, 0, sm, acc);

        u16* outp = vT + ((size_t)b << 20);
        #pragma unroll
        for (int nf = 0; nf < 4; ++nf) {
            int d = wn + nf * 16 + p;
            float bvv = bv[d];
            #pragma unroll
            for (int mf = 0; mf < 8; ++mf) {
                #pragma unroll
                for (int r = 0; r < 4; ++r) {
                    int row = m0 + wm + mf * 16 + g * 4 + r;
                    outp[(size_t)row * 256 + d] = f2bf(acc[mf][nf][r] + bvv);
                }
            }
        }
    }
}

// ---------------------------------------------------------------------------
// K2: score partials, split-K=8. grid (8=split, 1, 16=b), 512 threads.
// K-slice = split*512 (pointer offset), NT=16.
// ---------------------------------------------------------------------------
__global__ __launch_bounds__(512, 2) void k2_scores(
    const u16* __restrict__ q, const u16* __restrict__ kmat, float* __restrict__ spart)
{
    __shared__ u16 sm[65536];
    const int b = blockIdx.z;
    const int split = blockIdx.x;
    const u16* A = q    + ((size_t)b << 20) + split * 512;
    const u16* B = kmat + ((size_t)b << 20) + split * 512;

    f32x4 acc[8][4] = {};
    gemm256<16>(A, 4096, 0, 1, B, 4096, 0, sm, acc);

    const int tid = threadIdx.x;
    const int l = tid & 63, w = tid >> 6;
    const int p = l & 15, g = l >> 4;
    const int wm = (w >> 2) * 128, wn = (w & 3) * 64;

    float* sp = spart + ((size_t)split * 16 + b) * 65536;
    #pragma unroll
    for (int mf = 0; mf < 8; ++mf)
        #pragma unroll
        for (int nf = 0; nf < 4; ++nf) {
            int n = wn + nf * 16 + p;
            #pragma unroll
            for (int r = 0; r < 4; ++r) {
                int m = wm + mf * 16 + g * 4 + r;
                sp[(size_t)m * 256 + n] = acc[mf][nf][r] * 0.015625f;
            }
        }
}

// ---------------------------------------------------------------------------
// K3: reduce 8 split partials + softmax over d -> bf16 attn
// ---------------------------------------------------------------------------
__global__ __launch_bounds__(256) void k3_softmax(
    const float* __restrict__ sp, u16* __restrict__ attn)
{
    const int row = blockIdx.x;
    const int tid = threadIdx.x;
    const size_t STRIDE = (size_t)16 * 65536;
    const size_t base = (size_t)row * 256 + tid;

    float s = 0.f;
    #pragma unroll
    for (int i = 0; i < 8; ++i) s += sp[base + i * STRIDE];

    __shared__ float red[4];
    float m = s;
    #pragma unroll
    for (int off = 32; off >= 1; off >>= 1) m = fmaxf(m, __shfl_xor(m, off));
    if ((tid & 63) == 0) red[tid >> 6] = m;
    __syncthreads();
    m = fmaxf(fmaxf(red[0], red[1]), fmaxf(red[2], red[3]));

    float e = expf(s - m);
    float t = e;
    #pragma unroll
    for (int off = 32; off >= 1; off >>= 1) t += __shfl_xor(t, off);
    __syncthreads();
    if ((tid & 63) == 0) red[tid >> 6] = t;
    __syncthreads();
    t = red[0] + red[1] + red[2] + red[3];

    attn[base] = f2bf(e / t);
}

// ---------------------------------------------------------------------------
// K4: outT3[b][sh][co][nh] = sum_d attn[b][co][d] * vT[b][16nh+sh][d]
// Per (b,sh): M=256 (nh via rstride-16 A rows), N=256 (co), K=256 (d), NT=8.
// grid (16=sh, 1, 16=b), 512 threads.
// ---------------------------------------------------------------------------
__global__ __launch_bounds__(512, 2) void k4_pv(
    const u16* __restrict__ attn, const u16* __restrict__ vT, u16* __restrict__ outT3)
{
    __shared__ u16 sm[65536];
    const int b  = blockIdx.z;
    const int sh = blockIdx.x;
    const u16* A = vT   + ((size_t)b << 20);   // rows 16m+sh
    const u16* B = attn + ((size_t)b << 16);

    f32x4 acc[8][4] = {};
    gemm256<8>(A, 256, sh, 16, B, 256, 0, sm, acc);

    const int tid = threadIdx.x;
    const int l = tid & 63, w = tid >> 6;
    const int p = l & 15, g = l >> 4;
    const int wm = (w >> 2) * 128, wn = (w & 3) * 64;

    u16* outp = outT3 + (((size_t)b * 16 + sh) << 16);
    #pragma unroll
    for (int mf = 0; mf < 8; ++mf)
        #pragma unroll
        for (int nf = 0; nf < 4; ++nf) {
            int co  = wn + nf * 16 + p;
            int nh0 = wm + mf * 16 + g * 4;
            u16x4 u = {f2bf(acc[mf][nf][0]), f2bf(acc[mf][nf][1]),
                       f2bf(acc[mf][nf][2]), f2bf(acc[mf][nf][3])};
            *(u16x4*)(outp + (size_t)co * 256 + nh0) = u;
        }
}

// ---------------------------------------------------------------------------
// K5: final[b][c][sh*256+slo] = sum_nh Wo[c][nh] * outT3[b][sh][slo][nh] + bo[c]
// Per (b,sh): M=512 (c), N=256 (slo), K=256 (nh), NT=8. grid (1, 2, 256).
// ---------------------------------------------------------------------------
__global__ __launch_bounds__(512, 2) void k5_final(
    const u16* __restrict__ wo, const float* __restrict__ bo,
    const u16* __restrict__ outT3, float* __restrict__ out)
{
    __shared__ u16 sm[65536];
    const int bz = blockIdx.z;               // b*16 + sh
    const int b  = bz >> 4, sh = bz & 15;
    const int m0 = blockIdx.y * 256;
    const u16* B = outT3 + ((size_t)bz << 16);

    f32x4 acc[8][4] = {};
    gemm256<8>(wo, 256, m0, 1, B, 256, 0, sm, acc);

    const int tid = threadIdx.x;
    const int l = tid & 63, w = tid >> 6;
    const int p = l & 15, g = l >> 4;
    const int wm = (w >> 2) * 128, wn = (w & 3) * 64;

    float* ob = out + (size_t)b * 2097152 + (size_t)sh * 256;
    #pragma unroll
    for (int mf = 0; mf < 8; ++mf)
        #pragma unroll
        for (int nf = 0; nf < 4; ++nf) {
            int slo = wn + nf * 16 + p;
            #pragma unroll
            for (int r = 0; r < 4; ++r) {
                int m = m0 + wm + mf * 16 + g * 4 + r;
                ob[(size_t)m * 4096 + slo] = acc[mf][nf][r] + bo[m];
            }
        }
}

// ---------------------------------------------------------------------------
extern "C" void kernel_launch(void* const* d_in, const int* in_sizes, int n_in,
                              void* d_out, int out_size, void* d_ws, size_t ws_size,
                              hipStream_t stream) {
    (void)in_sizes; (void)n_in; (void)out_size; (void)ws_size;
    const float* x  = (const float*)d_in[0];
    const float* Wq = (const float*)d_in[1];
    const float* bq = (const float*)d_in[2];
    const float* Wk = (const float*)d_in[3];
    const float* bk = (const float*)d_in[4];
    const float* Wv = (const float*)d_in[5];
    const float* bv = (const float*)d_in[6];
    const float* Wo = (const float*)d_in[7];
    const float* bo = (const float*)d_in[8];
    float* out = (float*)d_out;

    char* ws = (char*)d_ws;
    u16* xT   = (u16*)(ws + 0);             // 67.1MB, dead after k1
    u16* q    = (u16*)(ws + 67108864);      // 33.5MB, dead after k2
    u16* kmat = (u16*)(ws + 100663296);     // 33.5MB, dead after k2
    u16* vT   = (u16*)(ws + 134217728);     // 33.5MB, dead after k4
    float* spart = (float*)(ws + 0);        // 33.5MB f32 (8 splits), aliases xT
    u16* attn    = (u16*)(ws + 67108864);   // 2MB, aliases q
    u16* outT3   = (u16*)(ws + 100663296);  // 33.5MB, aliases kmat
    u16* wqk  = (u16*)(ws + 167772160);     // 512KB [512][512] (q rows then k rows)
    u16* wv   = (u16*)(ws + 168296448);     // 256KB [256][512]
    u16* wo   = (u16*)(ws + 168558592);     // 256KB [512][256]

    k0_prep   <<<dim3(64, 8, 17), dim3(256), 0, stream>>>(x, xT, Wq, Wk, Wv, Wo, wqk, wv, wo);
    k1_qkv    <<<dim3(16, 3, 16), dim3(512), 0, stream>>>(wqk, wv, bq, bk, bv, xT, q, kmat, vT);
    k2_scores <<<dim3(8, 1, 16),  dim3(512), 0, stream>>>(q, kmat, spart);
    k3_softmax<<<dim3(4096),      dim3(256), 0, stream>>>(spart, attn);
    k4_pv     <<<dim3(16, 1, 16), dim3(512), 0, stream>>>(attn, vT, outT3);
    k5_final  <<<dim3(1, 2, 256), dim3(512), 0, stream>>>(wo, bo, outT3, out);
}